// Round 7
// baseline (359.697 us; speedup 1.0000x reference)
//
#include <hip/hip_runtime.h>

// Problem constants (B, L_IN, D) = (4, 4096, 1024)
#define BB 4
#define LL 4096
#define DD 1024
#define SS2 128  // number of scan chunks
#define TT2 32   // chunk length (SS2*TT2 == LL); 32 x uint2 = 64 VGPR reg-cache

typedef __attribute__((ext_vector_type(4))) float  floatx4;
typedef __attribute__((ext_vector_type(8))) short  shortx8;

static __device__ __forceinline__ unsigned short f2bf(float f) {
    unsigned int u = __float_as_uint(f);
    u += 0x7fffu + ((u >> 16) & 1u);           // round-to-nearest-even
    return (unsigned short)(u >> 16);
}
static __device__ __forceinline__ float bf2f(unsigned short h) {
    return __uint_as_float(((unsigned int)h) << 16);
}

// ---------------- merged f32 -> bf16 cast (inputs + Wi + Wo) ----------------
#define NIN4 (BB * LL * DD / 4)          // 4194304
#define NW4  (2 * DD * DD / 4)           // 524288
__global__ void cast_all_kernel(const float4* __restrict__ s_in, ushort4* __restrict__ d_inb,
                                const float4* __restrict__ s_wi, ushort4* __restrict__ d_wib,
                                const float4* __restrict__ s_wo, ushort4* __restrict__ d_wob) {
    int i = blockIdx.x * blockDim.x + threadIdx.x;
    const float4* s; ushort4* d; int j;
    if (i < NIN4)                 { s = s_in; d = d_inb; j = i; }
    else if (i < NIN4 + NW4)      { s = s_wi; d = d_wib; j = i - NIN4; }
    else                          { s = s_wo; d = d_wob; j = i - NIN4 - NW4; }
    float4 v = s[j];
    ushort4 o;
    o.x = f2bf(v.x); o.y = f2bf(v.y); o.z = f2bf(v.z); o.w = f2bf(v.w);
    d[j] = o;
}

// ---------------- bf16 GEMM: C[M,N] = A[M,K] * B[N,K]^T + bias ----------------
// R5 structure, unchanged (measured: 0 bank conflicts, ~735 TF):
// 16x16x32 MFMA 4x4/wave, global_load_lds w=16, BK=64 (32 KB LDS), XCD remap.
// LDS chunk q (16B) holds row=q>>3, k8 = (q&7) ^ (row&7)  [3-bit XOR swizzle].
// EPI==0: store bf16 (no relu). EPI==1: store f32 with relu.
template<int K, int NT, int EPI>
__global__ __launch_bounds__(256)
void gemm_bt(const unsigned short* __restrict__ A,
             const unsigned short* __restrict__ B,
             const float* __restrict__ bias,
             void* __restrict__ Cp) {
    constexpr int N = NT * 128;
    __shared__ __align__(16) short As[128 * 64];
    __shared__ __align__(16) short Bs[128 * 64];

    const int tid = threadIdx.x;
    const int b   = blockIdx.x;
    const int xcd = b & 7;
    const int i2  = b >> 3;
    const int tileM = ((i2 / NT) * 8 + xcd) * 128;
    const int tileN = (i2 % NT) * 128;

    const int lane  = tid & 63;
    const int wave  = tid >> 6;
    const int wm    = (wave >> 1) * 64;
    const int wn    = (wave & 1) * 64;
    const int r16   = lane & 15;
    const int quad  = lane >> 4;

    floatx4 acc[4][4] = {};

    int rowS[4], colS[4];
#pragma unroll
    for (int n = 0; n < 4; ++n) {
        const int q = tid + n * 256;
        rowS[n] = q >> 3;
        colS[n] = ((q & 7) ^ (rowS[n] & 7)) * 8;
    }
    const int ldsBase = (tid & ~63) * 8;

    const int fx = r16 & 7;

    for (int k0 = 0; k0 < K; k0 += 64) {
#pragma unroll
        for (int n = 0; n < 4; ++n) {
            __builtin_amdgcn_global_load_lds(
                (const __attribute__((address_space(1))) void*)&A[(size_t)(tileM + rowS[n]) * K + k0 + colS[n]],
                (__attribute__((address_space(3))) void*)&As[ldsBase + n * 2048], 16, 0, 0);
            __builtin_amdgcn_global_load_lds(
                (const __attribute__((address_space(1))) void*)&B[(size_t)(tileN + rowS[n]) * K + k0 + colS[n]],
                (__attribute__((address_space(3))) void*)&Bs[ldsBase + n * 2048], 16, 0, 0);
        }
        __syncthreads();

#pragma unroll
        for (int kk = 0; kk < 2; ++kk) {
            const int slot = ((kk * 4 + quad) ^ fx) * 8;
            shortx8 af[4], bfv[4];
#pragma unroll
            for (int i = 0; i < 4; ++i)
                af[i] = *(const shortx8*)(&As[(wm + i * 16 + r16) * 64 + slot]);
#pragma unroll
            for (int j = 0; j < 4; ++j)
                bfv[j] = *(const shortx8*)(&Bs[(wn + j * 16 + r16) * 64 + slot]);
#pragma unroll
            for (int i = 0; i < 4; ++i)
#pragma unroll
                for (int j = 0; j < 4; ++j)
                    acc[i][j] = __builtin_amdgcn_mfma_f32_16x16x32_bf16(
                        af[i], bfv[j], acc[i][j], 0, 0, 0);
        }
        __syncthreads();
    }

#pragma unroll
    for (int i = 0; i < 4; ++i) {
#pragma unroll
        for (int j = 0; j < 4; ++j) {
            const int col = tileN + wn + j * 16 + r16;
            const float bv = bias[col];
#pragma unroll
            for (int r = 0; r < 4; ++r) {
                const int row = tileM + wm + i * 16 + quad * 4 + r;
                float v = acc[i][j][r] + bv;
                if (EPI == 0) {
                    ((unsigned short*)Cp)[(size_t)row * N + col] = f2bf(v);
                } else {
                    ((float*)Cp)[(size_t)row * N + col] = fmaxf(v, 0.0f);
                }
            }
        }
    }
}

// ---------------- scan phase A: per-chunk local ends, reg-batched loads ----------------
// grid (2, SS2, BB) x 256 = 1024 blocks (4/CU). 2 channels/thread; the 32 chunk
// loads are issued back-to-back into a register cache (latency-hiding), then the
// dependent scan runs on registers. Eend: [SS2][B*D] float2.
__global__ __launch_bounds__(256)
void scanA(const unsigned short* __restrict__ u,
           const float* __restrict__ plog,
           float2* __restrict__ Eend) {
    const int d0 = (blockIdx.x * 256 + threadIdx.x) * 2;
    const int c = blockIdx.y, b = blockIdx.z;
    const float v0  = expf(plog[d0]),      v1  = expf(plog[d0 + 1]);
    const float th0 = expf(plog[DD + d0]), th1 = expf(plog[DD + d0 + 1]);
    const float a0 = expf(-v0), a1 = expf(-v1);
    const float lr0 = a0 * cosf(th0), li0 = a0 * sinf(th0);
    const float lr1 = a1 * cosf(th1), li1 = a1 * sinf(th1);

    uint2 uc[TT2];
    const unsigned short* up = u + (size_t)(b * LL + c * TT2) * (2 * DD) + 2 * d0;
#pragma unroll
    for (int t = 0; t < TT2; ++t)
        uc[t] = *(const uint2*)(up + (size_t)t * (2 * DD));

    float zr0 = 0.f, zi0 = 0.f, zr1 = 0.f, zi1 = 0.f;
#pragma unroll
    for (int t = 0; t < TT2; ++t) {
        float xr0 = bf2f((unsigned short)(uc[t].x & 0xffffu));
        float xi0 = bf2f((unsigned short)(uc[t].x >> 16));
        float xr1 = bf2f((unsigned short)(uc[t].y & 0xffffu));
        float xi1 = bf2f((unsigned short)(uc[t].y >> 16));
        float w;
        w = lr0 * zr0 - li0 * zi0 + xr0; zi0 = lr0 * zi0 + li0 * zr0 + xi0; zr0 = w;
        w = lr1 * zr1 - li1 * zi1 + xr1; zi1 = lr1 * zi1 + li1 * zr1 + xi1; zr1 = w;
    }
    *(float4*)&Eend[(size_t)c * (BB * DD) + b * DD + d0] =
        make_float4(zr0, zi0, zr1, zi1);
}

// ---------------- scan phase C: carry prefix + fix-up + gamma, reg-batched ----------------
// xr layout: [B*L, 2D] with col d = gamma*Re(y), col DD+d = gamma*Im(y)
__global__ __launch_bounds__(256)
void scanC(const unsigned short* __restrict__ u,
           const float* __restrict__ plog,
           const float2* __restrict__ Eend,
           unsigned short* __restrict__ xr) {
    const int d0 = (blockIdx.x * 256 + threadIdx.x) * 2;
    const int c = blockIdx.y, b = blockIdx.z;
    const float v0  = expf(plog[d0]),      v1  = expf(plog[d0 + 1]);
    const float th0 = expf(plog[DD + d0]), th1 = expf(plog[DD + d0 + 1]);
    const float g0  = expf(plog[2 * DD + d0]), g1 = expf(plog[2 * DD + d0 + 1]);
    const float a0 = expf(-v0), a1 = expf(-v1);
    const float lr0 = a0 * cosf(th0), li0 = a0 * sinf(th0);
    const float lr1 = a1 * cosf(th1), li1 = a1 * sinf(th1);

    // batch-load this chunk of u into registers first (loads in flight while
    // the carry prefix below chews on L2-resident Eend)
    uint2 uc[TT2];
    const unsigned short* up = u + (size_t)(b * LL + c * TT2) * (2 * DD) + 2 * d0;
#pragma unroll
    for (int t = 0; t < TT2; ++t)
        uc[t] = *(const uint2*)(up + (size_t)t * (2 * DD));

    // carry into chunk c: prefix over earlier chunks with Lambda = lambda^TT2
    const float aT0 = expf(-(float)TT2 * v0), aT1 = expf(-(float)TT2 * v1);
    const float Lr0 = aT0 * cosf((float)TT2 * th0), Li0 = aT0 * sinf((float)TT2 * th0);
    const float Lr1 = aT1 * cosf((float)TT2 * th1), Li1 = aT1 * sinf((float)TT2 * th1);
    float yr0 = 0.f, yi0 = 0.f, yr1 = 0.f, yi1 = 0.f;
    for (int cc = 0; cc < c; ++cc) {
        float4 e = *(const float4*)&Eend[(size_t)cc * (BB * DD) + b * DD + d0];
        float w;
        w = Lr0 * yr0 - Li0 * yi0 + e.x; yi0 = Lr0 * yi0 + Li0 * yr0 + e.y; yr0 = w;
        w = Lr1 * yr1 - Li1 * yi1 + e.z; yi1 = Lr1 * yi1 + Li1 * yr1 + e.w; yr1 = w;
    }

    unsigned short* xp = xr + (size_t)(b * LL + c * TT2) * (2 * DD) + d0;
#pragma unroll
    for (int t = 0; t < TT2; ++t) {
        float xr0 = bf2f((unsigned short)(uc[t].x & 0xffffu));
        float xi0 = bf2f((unsigned short)(uc[t].x >> 16));
        float xr1 = bf2f((unsigned short)(uc[t].y & 0xffffu));
        float xi1 = bf2f((unsigned short)(uc[t].y >> 16));
        float w;
        w = lr0 * yr0 - li0 * yi0 + xr0; yi0 = lr0 * yi0 + li0 * yr0 + xi0; yr0 = w;
        w = lr1 * yr1 - li1 * yi1 + xr1; yi1 = lr1 * yi1 + li1 * yr1 + xi1; yr1 = w;
        *(unsigned int*)&xp[(size_t)t * (2 * DD)] =
            (unsigned int)f2bf(g0 * yr0) | ((unsigned int)f2bf(g1 * yr1) << 16);
        *(unsigned int*)&xp[(size_t)t * (2 * DD) + DD] =
            (unsigned int)f2bf(g0 * yi0) | ((unsigned int)f2bf(g1 * yi1) << 16);
    }
}

extern "C" void kernel_launch(void* const* d_in, const int* in_sizes, int n_in,
                              void* d_out, int out_size, void* d_ws, size_t ws_size,
                              hipStream_t stream) {
    const float* inputs = (const float*)d_in[0];   // B*L*D = 16777216
    const float* Wi     = (const float*)d_in[1];   // 2D*D  = 2097152
    const float* bi     = (const float*)d_in[2];   // 2D
    const float* Wo     = (const float*)d_in[3];   // D*2D  = 2097152
    const float* bo     = (const float*)d_in[4];   // D
    const float* plog   = (const float*)d_in[5];   // 3*D
    float* out = (float*)d_out;

    const size_t M = (size_t)BB * LL;              // 16384
    unsigned short* u_bf  = (unsigned short*)d_ws;             // M*2D bf16  (64 MB)
    unsigned short* xr_bf = u_bf  + M * 2 * DD;                // M*2D bf16  (64 MB)
    unsigned short* in_bf = xr_bf + M * 2 * DD;                // M*D  bf16  (32 MB)
    unsigned short* Wi_bf = in_bf + M * DD;                    // 2D*D bf16  (4 MB)
    unsigned short* Wo_bf = Wi_bf + (size_t)2 * DD * DD;       // D*2D bf16  (4 MB)
    float2* Eend = (float2*)(Wo_bf + (size_t)2 * DD * DD);     // SS2*B*D f32x2 (4 MB)

    // merged bf16 casts (inputs + Wi + Wo) in one dispatch
    {
        int total4 = NIN4 + 2 * NW4;
        cast_all_kernel<<<total4 / 256, 256, 0, stream>>>(
            (const float4*)inputs, (ushort4*)in_bf,
            (const float4*)Wi,     (ushort4*)Wi_bf,
            (const float4*)Wo,     (ushort4*)Wo_bf);
    }

    // GEMM1: u[M, 2D] = in_bf[M, D] @ Wi^T + bi   (bf16 out), NT = 16
    gemm_bt<DD, 16, 0><<<(M / 128) * 16, 256, 0, stream>>>(
        in_bf, Wi_bf, bi, (void*)u_bf);

    // scan: 1024 blocks each (4/CU), reg-batched chunk loads
    scanA<<<dim3(DD / 512, SS2, BB), 256, 0, stream>>>(u_bf, plog, Eend);
    scanC<<<dim3(DD / 512, SS2, BB), 256, 0, stream>>>(u_bf, plog, Eend, xr_bf);

    // GEMM2: out[M, D] = relu(xr[M, 2D] @ Wo^T + bo)  (f32 out), NT = 8
    gemm_bt<2 * DD, 8, 1><<<(M / 128) * 8, 256, 0, stream>>>(
        xr_bf, Wo_bf, bo, (void*)out);
}

// Round 8
// 339.221 us; speedup vs baseline: 1.0604x; 1.0604x over previous
//
#include <hip/hip_runtime.h>

// Problem constants (B, L_IN, D) = (4, 4096, 1024)
#define BB 4
#define LL 4096
#define DD 1024
#define SS2 128  // number of scan chunks
#define TT2 32   // chunk length (SS2*TT2 == LL); 32 x uint2 = 64 VGPR reg-cache

typedef __attribute__((ext_vector_type(4))) float  floatx4;
typedef __attribute__((ext_vector_type(8))) short  shortx8;

static __device__ __forceinline__ unsigned short f2bf(float f) {
    unsigned int u = __float_as_uint(f);
    u += 0x7fffu + ((u >> 16) & 1u);           // round-to-nearest-even
    return (unsigned short)(u >> 16);
}
static __device__ __forceinline__ float bf2f(unsigned short h) {
    return __uint_as_float(((unsigned int)h) << 16);
}

// ---------------- merged f32 -> bf16 cast (inputs + Wi + Wo) ----------------
#define NIN4 (BB * LL * DD / 4)          // 4194304
#define NW4  (2 * DD * DD / 4)           // 524288
__global__ void cast_all_kernel(const float4* __restrict__ s_in, ushort4* __restrict__ d_inb,
                                const float4* __restrict__ s_wi, ushort4* __restrict__ d_wib,
                                const float4* __restrict__ s_wo, ushort4* __restrict__ d_wob) {
    int i = blockIdx.x * blockDim.x + threadIdx.x;
    const float4* s; ushort4* d; int j;
    if (i < NIN4)                 { s = s_in; d = d_inb; j = i; }
    else if (i < NIN4 + NW4)      { s = s_wi; d = d_wib; j = i - NIN4; }
    else                          { s = s_wo; d = d_wob; j = i - NIN4 - NW4; }
    float4 v = s[j];
    ushort4 o;
    o.x = f2bf(v.x); o.y = f2bf(v.y); o.z = f2bf(v.z); o.w = f2bf(v.w);
    d[j] = o;
}

// ---------------- bf16 GEMM: C[M,N] = A[M,K] * B[N,K]^T + bias ----------------
// R5 structure, unchanged (measured: 0 bank conflicts, ~735 TF):
// 16x16x32 MFMA 4x4/wave, global_load_lds w=16, BK=64 (32 KB LDS), XCD remap.
// LDS chunk q (16B) holds row=q>>3, k8 = (q&7) ^ (row&7)  [3-bit XOR swizzle].
// EPI==0: store bf16 (no relu). EPI==1: store f32 with relu.
template<int K, int NT, int EPI>
__global__ __launch_bounds__(256)
void gemm_bt(const unsigned short* __restrict__ A,
             const unsigned short* __restrict__ B,
             const float* __restrict__ bias,
             void* __restrict__ Cp) {
    constexpr int N = NT * 128;
    __shared__ __align__(16) short As[128 * 64];
    __shared__ __align__(16) short Bs[128 * 64];

    const int tid = threadIdx.x;
    const int b   = blockIdx.x;
    const int xcd = b & 7;
    const int i2  = b >> 3;
    const int tileM = ((i2 / NT) * 8 + xcd) * 128;
    const int tileN = (i2 % NT) * 128;

    const int lane  = tid & 63;
    const int wave  = tid >> 6;
    const int wm    = (wave >> 1) * 64;
    const int wn    = (wave & 1) * 64;
    const int r16   = lane & 15;
    const int quad  = lane >> 4;

    floatx4 acc[4][4] = {};

    int rowS[4], colS[4];
#pragma unroll
    for (int n = 0; n < 4; ++n) {
        const int q = tid + n * 256;
        rowS[n] = q >> 3;
        colS[n] = ((q & 7) ^ (rowS[n] & 7)) * 8;
    }
    const int ldsBase = (tid & ~63) * 8;

    const int fx = r16 & 7;

    for (int k0 = 0; k0 < K; k0 += 64) {
#pragma unroll
        for (int n = 0; n < 4; ++n) {
            __builtin_amdgcn_global_load_lds(
                (const __attribute__((address_space(1))) void*)&A[(size_t)(tileM + rowS[n]) * K + k0 + colS[n]],
                (__attribute__((address_space(3))) void*)&As[ldsBase + n * 2048], 16, 0, 0);
            __builtin_amdgcn_global_load_lds(
                (const __attribute__((address_space(1))) void*)&B[(size_t)(tileN + rowS[n]) * K + k0 + colS[n]],
                (__attribute__((address_space(3))) void*)&Bs[ldsBase + n * 2048], 16, 0, 0);
        }
        __syncthreads();

#pragma unroll
        for (int kk = 0; kk < 2; ++kk) {
            const int slot = ((kk * 4 + quad) ^ fx) * 8;
            shortx8 af[4], bfv[4];
#pragma unroll
            for (int i = 0; i < 4; ++i)
                af[i] = *(const shortx8*)(&As[(wm + i * 16 + r16) * 64 + slot]);
#pragma unroll
            for (int j = 0; j < 4; ++j)
                bfv[j] = *(const shortx8*)(&Bs[(wn + j * 16 + r16) * 64 + slot]);
#pragma unroll
            for (int i = 0; i < 4; ++i)
#pragma unroll
                for (int j = 0; j < 4; ++j)
                    acc[i][j] = __builtin_amdgcn_mfma_f32_16x16x32_bf16(
                        af[i], bfv[j], acc[i][j], 0, 0, 0);
        }
        __syncthreads();
    }

#pragma unroll
    for (int i = 0; i < 4; ++i) {
#pragma unroll
        for (int j = 0; j < 4; ++j) {
            const int col = tileN + wn + j * 16 + r16;
            const float bv = bias[col];
#pragma unroll
            for (int r = 0; r < 4; ++r) {
                const int row = tileM + wm + i * 16 + quad * 4 + r;
                float v = acc[i][j][r] + bv;
                if (EPI == 0) {
                    ((unsigned short*)Cp)[(size_t)row * N + col] = f2bf(v);
                } else {
                    ((float*)Cp)[(size_t)row * N + col] = fmaxf(v, 0.0f);
                }
            }
        }
    }
}

// ---------------- scan phase A: per-chunk local ends, reg-batched loads ----------------
// grid (2, SS2, BB) x 256 = 1024 blocks. 2 channels/thread; 32 chunk loads issued
// back-to-back into registers, then the dependent scan runs on registers.
__global__ __launch_bounds__(256)
void scanA(const unsigned short* __restrict__ u,
           const float* __restrict__ plog,
           float2* __restrict__ Eend) {
    const int d0 = (blockIdx.x * 256 + threadIdx.x) * 2;
    const int c = blockIdx.y, b = blockIdx.z;
    const float v0  = expf(plog[d0]),      v1  = expf(plog[d0 + 1]);
    const float th0 = expf(plog[DD + d0]), th1 = expf(plog[DD + d0 + 1]);
    const float a0 = expf(-v0), a1 = expf(-v1);
    const float lr0 = a0 * cosf(th0), li0 = a0 * sinf(th0);
    const float lr1 = a1 * cosf(th1), li1 = a1 * sinf(th1);

    uint2 uc[TT2];
    const unsigned short* up = u + (size_t)(b * LL + c * TT2) * (2 * DD) + 2 * d0;
#pragma unroll
    for (int t = 0; t < TT2; ++t)
        uc[t] = *(const uint2*)(up + (size_t)t * (2 * DD));

    float zr0 = 0.f, zi0 = 0.f, zr1 = 0.f, zi1 = 0.f;
#pragma unroll
    for (int t = 0; t < TT2; ++t) {
        float xr0 = bf2f((unsigned short)(uc[t].x & 0xffffu));
        float xi0 = bf2f((unsigned short)(uc[t].x >> 16));
        float xr1 = bf2f((unsigned short)(uc[t].y & 0xffffu));
        float xi1 = bf2f((unsigned short)(uc[t].y >> 16));
        float w;
        w = lr0 * zr0 - li0 * zi0 + xr0; zi0 = lr0 * zi0 + li0 * zr0 + xi0; zr0 = w;
        w = lr1 * zr1 - li1 * zi1 + xr1; zi1 = lr1 * zi1 + li1 * zr1 + xi1; zr1 = w;
    }
    *(float4*)&Eend[(size_t)c * (BB * DD) + b * DD + d0] =
        make_float4(zr0, zi0, zr1, zi1);
}

// ---------------- scan phase B: carries over chunk ends (tiny, reg-batched) ----------------
// 2048 threads; thread handles channel pair (b, d0). Loads Eend in groups of 16
// (all 16 in flight), runs the 16-step FMA chain, stores 16 Cin values.
// Cin[c] = state at end of chunk c-1 (carry INTO chunk c).
__global__ __launch_bounds__(256)
void scanB(const float2* __restrict__ Eend,
           const float* __restrict__ plog,
           float2* __restrict__ Cin) {
    const int idx = blockIdx.x * 256 + threadIdx.x;   // 0 .. B*D/2-1
    const int b  = idx / (DD / 2);
    const int d0 = (idx % (DD / 2)) * 2;
    const float v0  = expf(plog[d0]),      v1  = expf(plog[d0 + 1]);
    const float th0 = expf(plog[DD + d0]), th1 = expf(plog[DD + d0 + 1]);
    const float aT0 = expf(-(float)TT2 * v0), aT1 = expf(-(float)TT2 * v1);
    const float Lr0 = aT0 * cosf((float)TT2 * th0), Li0 = aT0 * sinf((float)TT2 * th0);
    const float Lr1 = aT1 * cosf((float)TT2 * th1), Li1 = aT1 * sinf((float)TT2 * th1);

    const size_t base = (size_t)b * DD + d0;
    float yr0 = 0.f, yi0 = 0.f, yr1 = 0.f, yi1 = 0.f;
#pragma unroll
    for (int g = 0; g < SS2 / 16; ++g) {
        float4 eb[16], cb[16];
#pragma unroll
        for (int t = 0; t < 16; ++t)
            eb[t] = *(const float4*)&Eend[(size_t)(g * 16 + t) * (BB * DD) + base];
#pragma unroll
        for (int t = 0; t < 16; ++t) {
            cb[t] = make_float4(yr0, yi0, yr1, yi1);
            float w;
            w = Lr0 * yr0 - Li0 * yi0 + eb[t].x; yi0 = Lr0 * yi0 + Li0 * yr0 + eb[t].y; yr0 = w;
            w = Lr1 * yr1 - Li1 * yi1 + eb[t].z; yi1 = Lr1 * yi1 + Li1 * yr1 + eb[t].w; yr1 = w;
        }
#pragma unroll
        for (int t = 0; t < 16; ++t)
            *(float4*)&Cin[(size_t)(g * 16 + t) * (BB * DD) + base] = cb[t];
    }
}

// ---------------- scan phase C: single carry load + fix-up + gamma ----------------
// xr layout: [B*L, 2D] with col d = gamma*Re(y), col DD+d = gamma*Im(y)
__global__ __launch_bounds__(256)
void scanC(const unsigned short* __restrict__ u,
           const float* __restrict__ plog,
           const float2* __restrict__ Cin,
           unsigned short* __restrict__ xr) {
    const int d0 = (blockIdx.x * 256 + threadIdx.x) * 2;
    const int c = blockIdx.y, b = blockIdx.z;
    const float v0  = expf(plog[d0]),      v1  = expf(plog[d0 + 1]);
    const float th0 = expf(plog[DD + d0]), th1 = expf(plog[DD + d0 + 1]);
    const float g0  = expf(plog[2 * DD + d0]), g1 = expf(plog[2 * DD + d0 + 1]);
    const float a0 = expf(-v0), a1 = expf(-v1);
    const float lr0 = a0 * cosf(th0), li0 = a0 * sinf(th0);
    const float lr1 = a1 * cosf(th1), li1 = a1 * sinf(th1);

    // batch-load this chunk of u into registers (loads in flight while the
    // carry load + lambda setup complete)
    uint2 uc[TT2];
    const unsigned short* up = u + (size_t)(b * LL + c * TT2) * (2 * DD) + 2 * d0;
#pragma unroll
    for (int t = 0; t < TT2; ++t)
        uc[t] = *(const uint2*)(up + (size_t)t * (2 * DD));

    float4 cy = *(const float4*)&Cin[(size_t)c * (BB * DD) + b * DD + d0];
    float yr0 = cy.x, yi0 = cy.y, yr1 = cy.z, yi1 = cy.w;

    unsigned short* xp = xr + (size_t)(b * LL + c * TT2) * (2 * DD) + d0;
#pragma unroll
    for (int t = 0; t < TT2; ++t) {
        float xr0 = bf2f((unsigned short)(uc[t].x & 0xffffu));
        float xi0 = bf2f((unsigned short)(uc[t].x >> 16));
        float xr1 = bf2f((unsigned short)(uc[t].y & 0xffffu));
        float xi1 = bf2f((unsigned short)(uc[t].y >> 16));
        float w;
        w = lr0 * yr0 - li0 * yi0 + xr0; yi0 = lr0 * yi0 + li0 * yr0 + xi0; yr0 = w;
        w = lr1 * yr1 - li1 * yi1 + xr1; yi1 = lr1 * yi1 + li1 * yr1 + xi1; yr1 = w;
        *(unsigned int*)&xp[(size_t)t * (2 * DD)] =
            (unsigned int)f2bf(g0 * yr0) | ((unsigned int)f2bf(g1 * yr1) << 16);
        *(unsigned int*)&xp[(size_t)t * (2 * DD) + DD] =
            (unsigned int)f2bf(g0 * yi0) | ((unsigned int)f2bf(g1 * yi1) << 16);
    }
}

extern "C" void kernel_launch(void* const* d_in, const int* in_sizes, int n_in,
                              void* d_out, int out_size, void* d_ws, size_t ws_size,
                              hipStream_t stream) {
    const float* inputs = (const float*)d_in[0];   // B*L*D = 16777216
    const float* Wi     = (const float*)d_in[1];   // 2D*D  = 2097152
    const float* bi     = (const float*)d_in[2];   // 2D
    const float* Wo     = (const float*)d_in[3];   // D*2D  = 2097152
    const float* bo     = (const float*)d_in[4];   // D
    const float* plog   = (const float*)d_in[5];   // 3*D
    float* out = (float*)d_out;

    const size_t M = (size_t)BB * LL;              // 16384
    unsigned short* u_bf  = (unsigned short*)d_ws;             // M*2D bf16  (64 MB)
    unsigned short* xr_bf = u_bf  + M * 2 * DD;                // M*2D bf16  (64 MB)
    unsigned short* in_bf = xr_bf + M * 2 * DD;                // M*D  bf16  (32 MB)
    unsigned short* Wi_bf = in_bf + M * DD;                    // 2D*D bf16  (4 MB)
    unsigned short* Wo_bf = Wi_bf + (size_t)2 * DD * DD;       // D*2D bf16  (4 MB)
    float2* Eend = (float2*)(Wo_bf + (size_t)2 * DD * DD);     // SS2*B*D f32x2 (4 MB)
    float2* Cin  = Eend + (size_t)SS2 * BB * DD;               // SS2*B*D f32x2 (4 MB)

    // merged bf16 casts (inputs + Wi + Wo) in one dispatch
    {
        int total4 = NIN4 + 2 * NW4;
        cast_all_kernel<<<total4 / 256, 256, 0, stream>>>(
            (const float4*)inputs, (ushort4*)in_bf,
            (const float4*)Wi,     (ushort4*)Wi_bf,
            (const float4*)Wo,     (ushort4*)Wo_bf);
    }

    // GEMM1: u[M, 2D] = in_bf[M, D] @ Wi^T + bi   (bf16 out), NT = 16
    gemm_bt<DD, 16, 0><<<(M / 128) * 16, 256, 0, stream>>>(
        in_bf, Wi_bf, bi, (void*)u_bf);

    // 3-phase scan: local ends -> carries (tiny) -> fix-up
    scanA<<<dim3(DD / 512, SS2, BB), 256, 0, stream>>>(u_bf, plog, Eend);
    scanB<<<(BB * DD / 2) / 256, 256, 0, stream>>>(Eend, plog, Cin);
    scanC<<<dim3(DD / 512, SS2, BB), 256, 0, stream>>>(u_bf, plog, Cin, xr_bf);

    // GEMM2: out[M, D] = relu(xr[M, 2D] @ Wo^T + bo)  (f32 out), NT = 8
    gemm_bt<2 * DD, 8, 1><<<(M / 128) * 8, 256, 0, stream>>>(
        xr_bf, Wo_bf, bo, (void*)out);
}